// Round 1
// baseline (83.953 us; speedup 1.0000x reference)
//
#include <hip/hip_runtime.h>
#include <hip/hip_bf16.h>

using bf16x8  = __attribute__((ext_vector_type(8))) short;
using f32x4   = __attribute__((ext_vector_type(4))) float;
using ushort8 = __attribute__((ext_vector_type(8))) unsigned short;
using uint2v  = __attribute__((ext_vector_type(2))) unsigned int;

#define BB   32
#define CIN  128
#define COUT 128
#define PODS 2
#define HIN  56
#define WIN  56
#define HW   4096   // 64*64 padded spatial

__device__ __forceinline__ unsigned short bf16bits(float v) {
  __hip_bfloat16 h = __float2bfloat16(v);
  return reinterpret_cast<unsigned short&>(h);
}
__device__ __forceinline__ float bits2f(unsigned short u) {
  return __uint_as_float(((unsigned)u) << 16);
}

template<int LEN>
__device__ __forceinline__ void fwht_stage(float (&a)[64]) {
  #pragma unroll
  for (int i = 0; i < 64; i += 2*LEN) {
    #pragma unroll
    for (int j = 0; j < LEN; ++j) {
      float u = a[i+j], v = a[i+j+LEN];
      a[i+j]     = u + v;
      a[i+j+LEN] = u - v;
    }
  }
}
__device__ __forceinline__ void fwht64(float (&a)[64]) {
  fwht_stage<1>(a); fwht_stage<2>(a); fwht_stage<4>(a);
  fwht_stage<8>(a); fwht_stage<16>(a); fwht_stage<32>(a);
}

// ---- tiny: conv_w f32 -> bf16 ----
__global__ void k_wconv(const float* __restrict__ w, unsigned short* __restrict__ Wb) {
  int i = blockIdx.x * 256 + threadIdx.x;
  if (i < PODS*COUT*CIN) Wb[i] = bf16bits(w[i]);
}

// ---- forward 2D FWHT per (b,c); pad 56x56 -> 64x64; write bf16 [b][c][hw] ----
__global__ __launch_bounds__(64) void k_fwht_fwd(const float* __restrict__ x,
                                                 unsigned short* __restrict__ F) {
  const int bc   = blockIdx.x;
  const int lane = threadIdx.x;          // = w column
  const float* xp = x + (size_t)bc * (HIN*WIN);

  float a[64];
  #pragma unroll
  for (int h = 0; h < 64; ++h) a[h] = 0.f;
  if (lane < WIN) {
    #pragma unroll
    for (int h = 0; h < HIN; ++h) a[h] = xp[h*WIN + lane];
  }
  fwht64(a);                              // transform over h (thread-local)

  __shared__ float t[64][65];
  #pragma unroll
  for (int k = 0; k < 64; ++k) t[k][lane] = a[k];
  __syncthreads();
  #pragma unroll
  for (int w = 0; w < 64; ++w) a[w] = t[lane][w];   // thread now owns row kh=lane
  fwht64(a);                              // transform over w

  unsigned short* Fp = F + (size_t)bc * HW + lane*64;
  #pragma unroll
  for (int j = 0; j < 8; ++j) {
    ushort8 v;
    #pragma unroll
    for (int e = 0; e < 8; ++e) v[e] = bf16bits(a[j*8 + e]);
    *reinterpret_cast<ushort8*>(Fp + j*8) = v;
  }
}

// ---- mixing: f6[b,o,hw] = softthr( sum_p sum_i W[p,o,i]*F[b,i,hw]*v[p,hw] ) ----
// block = (b, 128-wide hw slice); 4 waves; wave owns 32 o-rows.
__global__ __launch_bounds__(256, 2) void k_mix(const unsigned short* F,    // may alias G
                                                const unsigned short* __restrict__ Wb,
                                                const float* __restrict__ lv,
                                                const float* __restrict__ T,
                                                unsigned short* G) {
  const int b    = blockIdx.x >> 5;
  const int hwb  = blockIdx.x & 31;      // hw0 = hwb*128
  const int tid  = threadIdx.x;
  const int wave = tid >> 6;
  const int l    = tid & 63;

  __shared__ __align__(16) char Blds[PODS][32768];   // [pod][128 rows x 256B], XOR-swizzled

  // A fragments (conv_w) in registers: [pod][tm][kk]
  const int arow = l & 15;
  const int acol = (l >> 4) * 8;
  bf16x8 afr[PODS][2][4];
  #pragma unroll
  for (int p = 0; p < PODS; ++p)
    #pragma unroll
    for (int tm = 0; tm < 2; ++tm)
      #pragma unroll
      for (int kk = 0; kk < 4; ++kk) {
        int o = wave*32 + tm*16 + arow;
        size_t off = ((size_t)(p*COUT + o))*CIN + kk*32 + acol;
        afr[p][tm][kk] = *reinterpret_cast<const bf16x8*>(Wb + off);
      }

  // stage B tiles: Blds[p][hw_local][i] bf16 (row = 256B), v-scaled
  const int hwl  = (wave & 1)*64 + l;     // 0..127
  const int ib   = (wave >> 1)*64;        // i half
  const int hwg  = hwb*128 + hwl;
  const float v0 = expf(lv[hwg]);
  const float v1 = expf(lv[HW + hwg]);
  const unsigned short* Fb = F + (size_t)b * CIN * HW;
  const int rowbase = hwl * 256;
  const int sw      = (hwl & 7) << 4;
  #pragma unroll
  for (int it = 0; it < 16; ++it) {
    int i0 = ib + it*4;
    float f0 = bits2f(Fb[(size_t)(i0+0)*HW + hwg]);
    float f1 = bits2f(Fb[(size_t)(i0+1)*HW + hwg]);
    float f2 = bits2f(Fb[(size_t)(i0+2)*HW + hwg]);
    float f3 = bits2f(Fb[(size_t)(i0+3)*HW + hwg]);
    int boff = rowbase + ((i0*2) ^ sw);
    {
      unsigned r0 = (unsigned)bf16bits(f0*v0) | ((unsigned)bf16bits(f1*v0) << 16);
      unsigned r1 = (unsigned)bf16bits(f2*v0) | ((unsigned)bf16bits(f3*v0) << 16);
      uint2v val = {r0, r1};
      *reinterpret_cast<uint2v*>(&Blds[0][boff]) = val;
    }
    {
      unsigned r0 = (unsigned)bf16bits(f0*v1) | ((unsigned)bf16bits(f1*v1) << 16);
      unsigned r1 = (unsigned)bf16bits(f2*v1) | ((unsigned)bf16bits(f3*v1) << 16);
      uint2v val = {r0, r1};
      *reinterpret_cast<uint2v*>(&Blds[1][boff]) = val;
    }
  }
  __syncthreads();

  // MFMA: per wave 2 tm x 8 t x 4 kk x 2 pods
  f32x4 acc[2][8];
  #pragma unroll
  for (int tm = 0; tm < 2; ++tm)
    #pragma unroll
    for (int t = 0; t < 8; ++t)
      acc[tm][t] = (f32x4){0.f, 0.f, 0.f, 0.f};

  #pragma unroll
  for (int t = 0; t < 8; ++t) {
    int row = t*16 + (l & 15);
    int rb  = row * 256;
    int s2  = (row & 7) << 4;
    #pragma unroll
    for (int kk = 0; kk < 4; ++kk) {
      int cb = (kk*64 + (l >> 4)*16) ^ s2;
      bf16x8 b0 = *reinterpret_cast<const bf16x8*>(&Blds[0][rb + cb]);
      bf16x8 b1 = *reinterpret_cast<const bf16x8*>(&Blds[1][rb + cb]);
      #pragma unroll
      for (int tm = 0; tm < 2; ++tm) {
        acc[tm][t] = __builtin_amdgcn_mfma_f32_16x16x32_bf16(afr[0][tm][kk], b0, acc[tm][t], 0, 0, 0);
        acc[tm][t] = __builtin_amdgcn_mfma_f32_16x16x32_bf16(afr[1][tm][kk], b1, acc[tm][t], 0, 0, 0);
      }
    }
  }

  // soft-threshold + store bf16
  unsigned short* Gb = G + (size_t)b * COUT * HW + hwb*128;
  #pragma unroll
  for (int tm = 0; tm < 2; ++tm) {
    #pragma unroll
    for (int r = 0; r < 4; ++r) {
      int o = wave*32 + tm*16 + (l >> 4)*4 + r;
      float th = fmaxf(T[o], 0.f);
      #pragma unroll
      for (int t = 0; t < 8; ++t) {
        float f = acc[tm][t][r];
        float m = fabsf(f) - th;
        m = m > 0.f ? m : 0.f;
        Gb[(size_t)o*HW + t*16 + (l & 15)] = bf16bits(copysignf(m, f));
      }
    }
  }
}

// ---- inverse 2D FWHT per (b,o), /4096, crop, + x ----
__global__ __launch_bounds__(64) void k_ifwht(const unsigned short* __restrict__ G,
                                              const float* __restrict__ x,
                                              float* __restrict__ y) {
  const int bo   = blockIdx.x;
  const int lane = threadIdx.x;
  const unsigned short* Gp = G + (size_t)bo * HW;

  float a[64];
  #pragma unroll
  for (int h = 0; h < 64; ++h) a[h] = bits2f(Gp[h*64 + lane]);
  fwht64(a);

  __shared__ float t[64][65];
  #pragma unroll
  for (int k = 0; k < 64; ++k) t[k][lane] = a[k];
  __syncthreads();
  #pragma unroll
  for (int w = 0; w < 64; ++w) a[w] = t[lane][w];
  fwht64(a);

  if (lane < HIN) {
    const float* xp = x + (size_t)bo*(HIN*WIN) + lane*WIN;
    float*       yp = y + (size_t)bo*(HIN*WIN) + lane*WIN;
    #pragma unroll
    for (int w4 = 0; w4 < 14; ++w4) {
      float4 xv = reinterpret_cast<const float4*>(xp)[w4];
      float4 r;
      r.x = a[w4*4+0]*(1.f/4096.f) + xv.x;
      r.y = a[w4*4+1]*(1.f/4096.f) + xv.y;
      r.z = a[w4*4+2]*(1.f/4096.f) + xv.z;
      r.w = a[w4*4+3]*(1.f/4096.f) + xv.w;
      reinterpret_cast<float4*>(yp)[w4] = r;
    }
  }
}

extern "C" void kernel_launch(void* const* d_in, const int* in_sizes, int n_in,
                              void* d_out, int out_size, void* d_ws, size_t ws_size,
                              hipStream_t stream) {
  const float* x  = (const float*)d_in[0];
  const float* cw = (const float*)d_in[1];
  const float* lv = (const float*)d_in[2];
  const float* T  = (const float*)d_in[3];
  float* y = (float*)d_out;

  char* ws = (char*)d_ws;
  const size_t szW = 65536;                       // conv_w bf16 (32768*2 rounded up)
  const size_t szF = (size_t)BB * CIN * HW * 2;   // 33.5 MB
  const size_t szG = (size_t)BB * COUT * HW * 2;  // 33.5 MB

  unsigned short* Wb = (unsigned short*)ws;
  unsigned short* F  = (unsigned short*)(ws + szW);
  // alias G onto F if workspace is tight (safe: k_mix finishes all global F
  // reads before its staging __syncthreads, and each block touches only its
  // own (b, hw-slice) in both F and G)
  unsigned short* G  = (ws_size >= szW + szF + szG)
                     ? (unsigned short*)(ws + szW + szF) : F;

  k_wconv   <<<dim3((PODS*COUT*CIN + 255)/256), dim3(256), 0, stream>>>(cw, Wb);
  k_fwht_fwd<<<dim3(BB*CIN),  dim3(64),  0, stream>>>(x, F);
  k_mix     <<<dim3(BB*32),   dim3(256), 0, stream>>>(F, Wb, lv, T, G);
  k_ifwht   <<<dim3(BB*COUT), dim3(64),  0, stream>>>(G, x, y);
}